// Round 7
// baseline (490.916 us; speedup 1.0000x reference)
//
#include <hip/hip_runtime.h>
#include <hip/hip_bf16.h>

#define NB 4
#define SEQ 2048
#define DMODEL 512
#define HEADS 8
#define HDIM 64
// 0.125 * log2(e): scores come out in log2 domain -> exp2 is a single v_exp_f32
#define QKS_L2E 0.18033688011112042f

typedef __bf16 bf16_t;
typedef bf16_t bf16x8 __attribute__((ext_vector_type(8)));
typedef bf16_t bf16x4 __attribute__((ext_vector_type(4)));
typedef float f32x4 __attribute__((ext_vector_type(4)));

// XOR swizzle: rows are 64 bf16 = 128 B = 8x16B slots; spread column-slot by row&7.
__device__ __forceinline__ int swz(int row, int c16) {
    return (row << 7) + (((c16) ^ (row & 7)) << 4);
}

__device__ __forceinline__ bf16x4 cvt4(float4 v) {
    bf16x4 r;
    r[0] = (bf16_t)v.x; r[1] = (bf16_t)v.y; r[2] = (bf16_t)v.z; r[3] = (bf16_t)v.w;
    return r;
}

// ---------------------------------------------------------------------------
// K0: transpose + convert the 5 weight matrices (512x512 fp32 [k][n]) into
//     bf16 [n][k]. Order: Wq, Wg, Wk, Wv, Wo  (Wq|Wg contiguous for fused P1)
// ---------------------------------------------------------------------------
__global__ __launch_bounds__(256) void prep_weights(
    const float* __restrict__ Wq, const float* __restrict__ Wg,
    const float* __restrict__ Wk, const float* __restrict__ Wv,
    const float* __restrict__ Wo, bf16_t* __restrict__ out)
{
    __shared__ float t[64][65];
    const int m  = blockIdx.x >> 6;
    const int t2 = blockIdx.x & 63;
    const int tr = t2 >> 3, tc = t2 & 7;   // tr: k-tile, tc: n-tile
    const float* W = (m == 0) ? Wq : (m == 1) ? Wg : (m == 2) ? Wk : (m == 3) ? Wv : Wo;
    const int r0 = threadIdx.x >> 6;  // 0..3
    const int c  = threadIdx.x & 63;
#pragma unroll
    for (int i = 0; i < 64; i += 4) {
        int row = i + r0;
        t[row][c] = W[(size_t)(tr * 64 + row) * DMODEL + tc * 64 + c];
    }
    __syncthreads();
    bf16_t* o = out + (size_t)m * (DMODEL * DMODEL);
#pragma unroll
    for (int i = 0; i < 64; i += 4) {
        int row = i + r0;
        o[(size_t)(tc * 64 + row) * DMODEL + tr * 64 + c] = (bf16_t)t[c][row];
    }
}

// ---------------------------------------------------------------------------
// K1: projection GEMM, 128x128 tile, 8 waves (512 thr), BK=64
// __launch_bounds__(512, 4): 2 blocks/CU min -> 128-VGPR budget, no spill
// (spill at default heuristic's 64-VGPR budget was the R6 regression)
// MODE 0: A=q, B=[Wq_t;Wg_t] (N=1024): col<512 -> wq bf16 *QKS_L2E; else sigmoid->g
// MODE 1: A=k, B=Wk_t (N=512): plain bf16
// MODE 2: A=v, B=Wv_t (N=512): bf16 transposed -> (B,H,HDIM,SEQ)
// ---------------------------------------------------------------------------
template <int MODE>
__global__ __launch_bounds__(512, 4) void proj_gemm(
    const float* __restrict__ A, const bf16_t* __restrict__ Wt,
    const float* __restrict__ bias0, const float* __restrict__ bias1,
    bf16_t* __restrict__ out0, bf16_t* __restrict__ out1)
{
    constexpr int NT = (MODE == 0) ? 8 : 4;
    __shared__ __align__(16) char smA[16384];
    __shared__ __align__(16) char smB[16384];
    const int tid = threadIdx.x;
    const int lane = tid & 63, w = tid >> 6;
    const int nt = blockIdx.x & (NT - 1);
    const int mt = blockIdx.x / NT;
    const int m0 = mt << 7, n0 = nt << 7;
    const int wr = w >> 2, wc = w & 3;
    const int lr = lane & 15, lg = lane >> 4;

    f32x4 acc[4][2] = {};
    for (int kb = 0; kb < 8; ++kb) {
        const int k0 = kb * 64;
        __syncthreads();
#pragma unroll
        for (int i = 0; i < 4; ++i) {
            int f = tid + i * 512;
            int row = f >> 4, c4 = f & 15;
            float4 v = *(const float4*)(A + (size_t)(m0 + row) * DMODEL + k0 + c4 * 4);
            *(bf16x4*)(smA + swz(row, c4 >> 1) + ((c4 & 1) << 3)) = cvt4(v);
        }
#pragma unroll
        for (int i = 0; i < 2; ++i) {
            int f = tid + i * 512;
            int row = f >> 3, c16 = f & 7;
            uint4 v = *(const uint4*)(Wt + (size_t)(n0 + row) * DMODEL + k0 + c16 * 8);
            *(uint4*)(smB + swz(row, c16)) = v;
        }
        __syncthreads();
#pragma unroll
        for (int ks = 0; ks < 2; ++ks) {
            bf16x8 a[4], bb[2];
#pragma unroll
            for (int mi = 0; mi < 4; ++mi)
                a[mi] = *(const bf16x8*)(smA + swz(wr * 64 + mi * 16 + lr, lg + ks * 4));
#pragma unroll
            for (int ni = 0; ni < 2; ++ni)
                bb[ni] = *(const bf16x8*)(smB + swz(wc * 32 + ni * 16 + lr, lg + ks * 4));
#pragma unroll
            for (int mi = 0; mi < 4; ++mi)
#pragma unroll
                for (int ni = 0; ni < 2; ++ni)
                    acc[mi][ni] = __builtin_amdgcn_mfma_f32_16x16x32_bf16(a[mi], bb[ni], acc[mi][ni], 0, 0, 0);
        }
    }
#pragma unroll
    for (int mi = 0; mi < 4; ++mi) {
#pragma unroll
        for (int ni = 0; ni < 2; ++ni) {
            const int col = n0 + wc * 32 + ni * 16 + lr;
            const int row0 = m0 + wr * 64 + mi * 16 + lg * 4;
            if (MODE == 0) {
                const bool isG = col >= DMODEL;
                const int c = isG ? col - DMODEL : col;
                const float bb = isG ? bias1[c] : bias0[c];
#pragma unroll
                for (int j = 0; j < 4; ++j) {
                    float x = acc[mi][ni][j] + bb;
                    bf16_t r = isG ? (bf16_t)(1.0f / (1.0f + __expf(-x)))
                                   : (bf16_t)(x * QKS_L2E);
                    (isG ? out1 : out0)[(size_t)(row0 + j) * DMODEL + c] = r;
                }
            } else if (MODE == 1) {
                const float bb = bias0[col];
#pragma unroll
                for (int j = 0; j < 4; ++j)
                    out0[(size_t)(row0 + j) * DMODEL + col] = (bf16_t)(acc[mi][ni][j] + bb);
            } else {
                const float bb = bias0[col];
                const int b = row0 >> 11, key = row0 & (SEQ - 1);
                const int h = col >> 6, d = col & 63;
                bf16x4 r;
#pragma unroll
                for (int j = 0; j < 4; ++j) r[j] = (bf16_t)(acc[mi][ni][j] + bb);
                *(bf16x4*)(out0 + ((size_t)(b * HEADS + h) * HDIM + d) * SEQ + key) = r;
            }
        }
    }
}

// ---------------------------------------------------------------------------
// K2: flash attention (softmax(QK^T)@V; bias term via K2b). Scores are tiny
// (|s_log2| < ~1.5) => NO max-tracking: p=exp2(s), per-lane partial row-sums,
// single cross-lane reduction at the end. wq_ carries 0.125*log2(e).
// Register double-buffered K/V staging (T14). __launch_bounds__(256, 4):
// 128-VGPR budget so the ~85 live VGPRs fit WITHOUT scratch spill (R6: the
// default budget spilled -> 305 MB/dispatch scratch writes, 157 us).
// ---------------------------------------------------------------------------
__global__ __launch_bounds__(256, 4) void attn_kernel(
    const bf16_t* __restrict__ wq, const bf16_t* __restrict__ wk,
    const bf16_t* __restrict__ wvt, bf16_t* __restrict__ attn_o)
{
    __shared__ __align__(16) char smK[8192];
    __shared__ __align__(16) char smV[8192];
    __shared__ __align__(16) char smP[8192];
    const int tid = threadIdx.x;
    const int lane = tid & 63, w = tid >> 6;
    const int bh = blockIdx.x & 31;
    const int qt = blockIdx.x >> 5;
    const int b = bh >> 3, h = bh & 7;
    const int q0 = qt << 6;
    const int lr = lane & 15, lg = lane >> 4;

    bf16x8 qf[2];
    {
        int row = q0 + w * 16 + lr;
        const bf16_t* p = wq + (size_t)(b * SEQ + row) * DMODEL + h * HDIM + lg * 8;
        qf[0] = *(const bf16x8*)(p);
        qf[1] = *(const bf16x8*)(p + 32);
    }
    const bf16_t* kbase = wk + (size_t)b * SEQ * DMODEL + h * HDIM;
    const bf16_t* vbase = wvt + (size_t)(b * HEADS + h) * HDIM * SEQ;
    // staging coords: i in {0,1}; f = tid + i*256; row = f>>3 (0..63), c16 = f&7
    const int srow0 = tid >> 3,        sc0 = tid & 7;
    const int srow1 = (tid + 256) >> 3, sc1 = (tid + 256) & 7;

    uint4 rk[2], rv[2];
    rk[0] = *(const uint4*)(kbase + (size_t)srow0 * DMODEL + sc0 * 8);
    rk[1] = *(const uint4*)(kbase + (size_t)srow1 * DMODEL + sc1 * 8);
    rv[0] = *(const uint4*)(vbase + (size_t)srow0 * SEQ + sc0 * 8);
    rv[1] = *(const uint4*)(vbase + (size_t)srow1 * SEQ + sc1 * 8);

    float lsum[4] = {0.f, 0.f, 0.f, 0.f};
    f32x4 oacc[4] = {};

    for (int kt = 0; kt < SEQ / 64; ++kt) {
        __syncthreads();   // previous tile's LDS reads complete
        *(uint4*)(smK + swz(srow0, sc0)) = rk[0];
        *(uint4*)(smK + swz(srow1, sc1)) = rk[1];
        *(uint4*)(smV + swz(srow0, sc0)) = rv[0];
        *(uint4*)(smV + swz(srow1, sc1)) = rv[1];
        __syncthreads();
        if (kt + 1 < SEQ / 64) {
            const int k0n = (kt + 1) * 64;
            rk[0] = *(const uint4*)(kbase + (size_t)(k0n + srow0) * DMODEL + sc0 * 8);
            rk[1] = *(const uint4*)(kbase + (size_t)(k0n + srow1) * DMODEL + sc1 * 8);
            rv[0] = *(const uint4*)(vbase + (size_t)srow0 * SEQ + k0n + sc0 * 8);
            rv[1] = *(const uint4*)(vbase + (size_t)srow1 * SEQ + k0n + sc1 * 8);
        }

        // S = Q @ K^T (log2-domain): rows=q (16), cols=keys (64)
        f32x4 s[4] = {};
#pragma unroll
        for (int ks = 0; ks < 2; ++ks) {
#pragma unroll
            for (int nf = 0; nf < 4; ++nf) {
                bf16x8 kbf = *(const bf16x8*)(smK + swz(nf * 16 + lr, lg + ks * 4));
                s[nf] = __builtin_amdgcn_mfma_f32_16x16x32_bf16(qf[ks], kbf, s[nf], 0, 0, 0);
            }
        }
        // p = 2^s ; accumulate per-lane partial row sums (reduce once at end)
#pragma unroll
        for (int nf = 0; nf < 4; ++nf) {
#pragma unroll
            for (int j = 0; j < 4; ++j) {
                float p = __builtin_amdgcn_exp2f(s[nf][j]);
                s[nf][j] = p;
                lsum[j] += p;
            }
        }
        // P -> per-wave LDS (bf16, swizzled); wave-private, no barrier needed
        char* pbase = smP + w * 2048;
#pragma unroll
        for (int nf = 0; nf < 4; ++nf) {
            int col = nf * 16 + lr;
#pragma unroll
            for (int j = 0; j < 4; ++j) {
                int row = lg * 4 + j;
                *(bf16_t*)(pbase + swz(row, col >> 3) + ((col & 7) << 1)) = (bf16_t)s[nf][j];
            }
        }
        // O += P @ V
#pragma unroll
        for (int ks = 0; ks < 2; ++ks) {
            bf16x8 pa = *(const bf16x8*)(pbase + swz(lr, lg + ks * 4));
#pragma unroll
            for (int nf = 0; nf < 4; ++nf) {
                bf16x8 vb = *(const bf16x8*)(smV + swz(nf * 16 + lr, lg + ks * 4));
                oacc[nf] = __builtin_amdgcn_mfma_f32_16x16x32_bf16(pa, vb, oacc[nf], 0, 0, 0);
            }
        }
    }
    float rinv[4];
#pragma unroll
    for (int j = 0; j < 4; ++j) {
        float t = lsum[j];
#pragma unroll
        for (int off = 1; off < 16; off <<= 1) t += __shfl_xor(t, off);
        rinv[j] = 1.0f / t;
    }
#pragma unroll
    for (int nf = 0; nf < 4; ++nf) {
        int col = h * HDIM + nf * 16 + lr;
#pragma unroll
        for (int j = 0; j < 4; ++j) {
            int row = q0 + w * 16 + lg * 4 + j;
            attn_o[(size_t)(b * SEQ + row) * DMODEL + col] = (bf16_t)(oacc[nf][j] * rinv[j]);
        }
    }
}

// ---------------------------------------------------------------------------
// K2b: Bv = bias @ wv   (batched: M=2048, N=512, K=2048), 128x128 tile
// ---------------------------------------------------------------------------
__global__ __launch_bounds__(512, 4) void biasv_gemm(
    const float* __restrict__ bias, const bf16_t* __restrict__ wvt,
    float* __restrict__ Bv)
{
    __shared__ __align__(16) char smA[16384];
    __shared__ __align__(16) char smB[16384];
    const int tid = threadIdx.x;
    const int lane = tid & 63, w = tid >> 6;
    const int nt = blockIdx.x & 3;
    const int mt = (blockIdx.x >> 2) & 15;
    const int b = blockIdx.x >> 6;
    const int m0 = mt << 7, n0 = nt << 7;
    const int wr = w >> 2, wc = w & 3;
    const int lr = lane & 15, lg = lane >> 4;

    f32x4 acc[4][2] = {};
    for (int kb = 0; kb < SEQ / 64; ++kb) {
        const int k0 = kb * 64;
        __syncthreads();
#pragma unroll
        for (int i = 0; i < 4; ++i) {
            int f = tid + i * 512;
            int row = f >> 4, c4 = f & 15;
            float4 v = *(const float4*)(bias + ((size_t)b * SEQ + m0 + row) * SEQ + k0 + c4 * 4);
            *(bf16x4*)(smA + swz(row, c4 >> 1) + ((c4 & 1) << 3)) = cvt4(v);
        }
#pragma unroll
        for (int i = 0; i < 2; ++i) {
            int f = tid + i * 512;
            int row = f >> 3, c16 = f & 7;
            int n = n0 + row;
            uint4 v = *(const uint4*)(wvt + ((size_t)(b * HEADS + (n >> 6)) * HDIM + (n & 63)) * SEQ + k0 + c16 * 8);
            *(uint4*)(smB + swz(row, c16)) = v;
        }
        __syncthreads();
#pragma unroll
        for (int ks = 0; ks < 2; ++ks) {
            bf16x8 a[4], bb[2];
#pragma unroll
            for (int mi = 0; mi < 4; ++mi)
                a[mi] = *(const bf16x8*)(smA + swz(wr * 64 + mi * 16 + lr, lg + ks * 4));
#pragma unroll
            for (int ni = 0; ni < 2; ++ni)
                bb[ni] = *(const bf16x8*)(smB + swz(wc * 32 + ni * 16 + lr, lg + ks * 4));
#pragma unroll
            for (int mi = 0; mi < 4; ++mi)
#pragma unroll
                for (int ni = 0; ni < 2; ++ni)
                    acc[mi][ni] = __builtin_amdgcn_mfma_f32_16x16x32_bf16(a[mi], bb[ni], acc[mi][ni], 0, 0, 0);
        }
    }
#pragma unroll
    for (int mi = 0; mi < 4; ++mi) {
#pragma unroll
        for (int ni = 0; ni < 2; ++ni) {
            int col = n0 + wc * 32 + ni * 16 + lr;
#pragma unroll
            for (int j = 0; j < 4; ++j) {
                int row = m0 + wr * 64 + mi * 16 + lg * 4 + j;
                Bv[((size_t)b * SEQ + row) * DMODEL + col] = acc[mi][ni][j];
            }
        }
    }
}

// ---------------------------------------------------------------------------
// K3: out = (g * (attn + Bv)) @ Wo + bo, 128x128 tile, fused A staging
// ---------------------------------------------------------------------------
__global__ __launch_bounds__(512, 4) void out_gemm(
    const bf16_t* __restrict__ atn, const float* __restrict__ Bvp,
    const bf16_t* __restrict__ gg, const bf16_t* __restrict__ Wot,
    const float* __restrict__ bo, float* __restrict__ out)
{
    __shared__ __align__(16) char smA[16384];
    __shared__ __align__(16) char smB[16384];
    const int tid = threadIdx.x;
    const int lane = tid & 63, w = tid >> 6;
    const int nt = blockIdx.x & 3;
    const int mt = blockIdx.x >> 2;
    const int m0 = mt << 7, n0 = nt << 7;
    const int wr = w >> 2, wc = w & 3;
    const int lr = lane & 15, lg = lane >> 4;

    f32x4 acc[4][2] = {};
    for (int kb = 0; kb < 8; ++kb) {
        const int k0 = kb * 64;
        __syncthreads();
#pragma unroll
        for (int i = 0; i < 2; ++i) {
            int f = tid + i * 512;
            int row = f >> 3, c8 = f & 7;
            size_t idx = (size_t)(m0 + row) * DMODEL + k0 + c8 * 8;
            bf16x8 a8 = *(const bf16x8*)(atn + idx);
            bf16x8 g8 = *(const bf16x8*)(gg + idx);
            float4 blo = *(const float4*)(Bvp + idx);
            float4 bhi = *(const float4*)(Bvp + idx + 4);
            bf16x8 r;
            r[0] = (bf16_t)((float)g8[0] * ((float)a8[0] + blo.x));
            r[1] = (bf16_t)((float)g8[1] * ((float)a8[1] + blo.y));
            r[2] = (bf16_t)((float)g8[2] * ((float)a8[2] + blo.z));
            r[3] = (bf16_t)((float)g8[3] * ((float)a8[3] + blo.w));
            r[4] = (bf16_t)((float)g8[4] * ((float)a8[4] + bhi.x));
            r[5] = (bf16_t)((float)g8[5] * ((float)a8[5] + bhi.y));
            r[6] = (bf16_t)((float)g8[6] * ((float)a8[6] + bhi.z));
            r[7] = (bf16_t)((float)g8[7] * ((float)a8[7] + bhi.w));
            *(bf16x8*)(smA + swz(row, c8)) = r;
        }
#pragma unroll
        for (int i = 0; i < 2; ++i) {
            int f = tid + i * 512;
            int row = f >> 3, c16 = f & 7;
            uint4 v = *(const uint4*)(Wot + (size_t)(n0 + row) * DMODEL + k0 + c16 * 8);
            *(uint4*)(smB + swz(row, c16)) = v;
        }
        __syncthreads();
#pragma unroll
        for (int ks = 0; ks < 2; ++ks) {
            bf16x8 a[4], bb[2];
#pragma unroll
            for (int mi = 0; mi < 4; ++mi)
                a[mi] = *(const bf16x8*)(smA + swz(wr * 64 + mi * 16 + lr, lg + ks * 4));
#pragma unroll
            for (int ni = 0; ni < 2; ++ni)
                bb[ni] = *(const bf16x8*)(smB + swz(wc * 32 + ni * 16 + lr, lg + ks * 4));
#pragma unroll
            for (int mi = 0; mi < 4; ++mi)
#pragma unroll
                for (int ni = 0; ni < 2; ++ni)
                    acc[mi][ni] = __builtin_amdgcn_mfma_f32_16x16x32_bf16(a[mi], bb[ni], acc[mi][ni], 0, 0, 0);
        }
    }
#pragma unroll
    for (int mi = 0; mi < 4; ++mi) {
#pragma unroll
        for (int ni = 0; ni < 2; ++ni) {
            int col = n0 + wc * 32 + ni * 16 + lr;
            float bb = bo[col];
#pragma unroll
            for (int j = 0; j < 4; ++j) {
                int row = m0 + wr * 64 + mi * 16 + lg * 4 + j;
                out[(size_t)row * DMODEL + col] = acc[mi][ni][j] + bb;
            }
        }
    }
}

// ---------------------------------------------------------------------------
extern "C" void kernel_launch(void* const* d_in, const int* in_sizes, int n_in,
                              void* d_out, int out_size, void* d_ws, size_t ws_size,
                              hipStream_t stream)
{
    const float* q    = (const float*)d_in[0];
    const float* k    = (const float*)d_in[1];
    const float* v    = (const float*)d_in[2];
    const float* bias = (const float*)d_in[3];
    const float* Wq   = (const float*)d_in[4];
    const float* bq   = (const float*)d_in[5];
    const float* Wk   = (const float*)d_in[6];
    const float* bk   = (const float*)d_in[7];
    const float* Wv   = (const float*)d_in[8];
    const float* bv   = (const float*)d_in[9];
    const float* Wg   = (const float*)d_in[10];
    const float* bg   = (const float*)d_in[11];
    const float* Wo   = (const float*)d_in[12];
    const float* bo   = (const float*)d_in[13];
    float* out = (float*)d_out;

    char* ws = (char*)d_ws;
    const size_t WSZ = (size_t)DMODEL * DMODEL;          // 262144 elems
    const size_t TOK = (size_t)NB * SEQ * DMODEL;        // 4.19M elems
    bf16_t* Wt   = (bf16_t*)ws;                          // [Wq;Wg;Wk;Wv;Wo]_t bf16
    bf16_t* wq_  = (bf16_t*)(ws + 5 * WSZ * 2);          // (B,Q,512) bf16, *0.125*log2e
    bf16_t* wk_  = wq_ + TOK;                            // (B,K,512) bf16
    bf16_t* wvt  = wk_ + TOK;                            // (B,H,64,K) bf16
    bf16_t* atn  = wvt + TOK;                            // (B,Q,512) bf16
    bf16_t* g_   = atn + TOK;                            // (B,Q,512) bf16
    float*  Bv_  = (float*)(g_ + TOK);                   // (B,Q,512) f32
    // total ws use: 2.6MB + 5*8MB + 16MB = ~58.6 MB

    prep_weights<<<320, 256, 0, stream>>>(Wq, Wg, Wk, Wv, Wo, Wt);
    proj_gemm<0><<<512, 512, 0, stream>>>(q, Wt,           bq, bg,      wq_, g_);
    proj_gemm<1><<<256, 512, 0, stream>>>(k, Wt + 2 * WSZ, bk, nullptr, wk_, nullptr);
    proj_gemm<2><<<256, 512, 0, stream>>>(v, Wt + 3 * WSZ, bv, nullptr, wvt, nullptr);
    attn_kernel<<<1024, 256, 0, stream>>>(wq_, wk_, wvt, atn);
    biasv_gemm<<<256, 512, 0, stream>>>(bias, wvt, Bv_);
    out_gemm<<<256, 512, 0, stream>>>(atn, Bv_, g_, Wt + 4 * WSZ, bo, out);
}

// Round 9
// 408.235 us; speedup vs baseline: 1.2025x; 1.2025x over previous
//
#include <hip/hip_runtime.h>
#include <hip/hip_bf16.h>

#define NB 4
#define SEQ 2048
#define DMODEL 512
#define HEADS 8
#define HDIM 64
// 0.125 * log2(e): scores come out in log2 domain -> exp2 is a single v_exp_f32
#define QKS_L2E 0.18033688011112042f

typedef __bf16 bf16_t;
typedef bf16_t bf16x8 __attribute__((ext_vector_type(8)));
typedef bf16_t bf16x4 __attribute__((ext_vector_type(4)));
typedef float f32x4 __attribute__((ext_vector_type(4)));

// XOR swizzle: rows are 64 bf16 = 128 B = 8x16B slots; spread column-slot by row&7.
__device__ __forceinline__ int swz(int row, int c16) {
    return (row << 7) + (((c16) ^ (row & 7)) << 4);
}

__device__ __forceinline__ bf16x4 cvt4(float4 v) {
    bf16x4 r;
    r[0] = (bf16_t)v.x; r[1] = (bf16_t)v.y; r[2] = (bf16_t)v.z; r[3] = (bf16_t)v.w;
    return r;
}

// ---------------------------------------------------------------------------
// K0: transpose + convert the 5 weight matrices (512x512 fp32 [k][n]) into
//     bf16 [n][k]. Order: Wq, Wg, Wk, Wv, Wo  (Wq|Wg contiguous for fused P1)
// ---------------------------------------------------------------------------
__global__ __launch_bounds__(256) void prep_weights(
    const float* __restrict__ Wq, const float* __restrict__ Wg,
    const float* __restrict__ Wk, const float* __restrict__ Wv,
    const float* __restrict__ Wo, bf16_t* __restrict__ out)
{
    __shared__ float t[64][65];
    const int m  = blockIdx.x >> 6;
    const int t2 = blockIdx.x & 63;
    const int tr = t2 >> 3, tc = t2 & 7;   // tr: k-tile, tc: n-tile
    const float* W = (m == 0) ? Wq : (m == 1) ? Wg : (m == 2) ? Wk : (m == 3) ? Wv : Wo;
    const int r0 = threadIdx.x >> 6;  // 0..3
    const int c  = threadIdx.x & 63;
#pragma unroll
    for (int i = 0; i < 64; i += 4) {
        int row = i + r0;
        t[row][c] = W[(size_t)(tr * 64 + row) * DMODEL + tc * 64 + c];
    }
    __syncthreads();
    bf16_t* o = out + (size_t)m * (DMODEL * DMODEL);
#pragma unroll
    for (int i = 0; i < 64; i += 4) {
        int row = i + r0;
        o[(size_t)(tc * 64 + row) * DMODEL + tr * 64 + c] = (bf16_t)t[c][row];
    }
}

// ---------------------------------------------------------------------------
// K1: projection GEMM, 128x128 tile, 8 waves (512 thr), BK=64
// MODE 0: A=q, B=[Wq_t;Wg_t] (N=1024): col<512 -> wq bf16 *QKS_L2E; else sigmoid->g
// MODE 1: A=k, B=Wk_t (N=512): plain bf16
// MODE 2: A=v, B=Wv_t (N=512): bf16 transposed -> (B,H,HDIM,SEQ)
// ---------------------------------------------------------------------------
template <int MODE>
__global__ __launch_bounds__(512) void proj_gemm(
    const float* __restrict__ A, const bf16_t* __restrict__ Wt,
    const float* __restrict__ bias0, const float* __restrict__ bias1,
    bf16_t* __restrict__ out0, bf16_t* __restrict__ out1)
{
    constexpr int NT = (MODE == 0) ? 8 : 4;
    __shared__ __align__(16) char smA[16384];
    __shared__ __align__(16) char smB[16384];
    const int tid = threadIdx.x;
    const int lane = tid & 63, w = tid >> 6;
    const int nt = blockIdx.x & (NT - 1);
    const int mt = blockIdx.x / NT;
    const int m0 = mt << 7, n0 = nt << 7;
    const int wr = w >> 2, wc = w & 3;
    const int lr = lane & 15, lg = lane >> 4;

    f32x4 acc[4][2] = {};
    for (int kb = 0; kb < 8; ++kb) {
        const int k0 = kb * 64;
        __syncthreads();
#pragma unroll
        for (int i = 0; i < 4; ++i) {
            int f = tid + i * 512;
            int row = f >> 4, c4 = f & 15;
            float4 v = *(const float4*)(A + (size_t)(m0 + row) * DMODEL + k0 + c4 * 4);
            *(bf16x4*)(smA + swz(row, c4 >> 1) + ((c4 & 1) << 3)) = cvt4(v);
        }
#pragma unroll
        for (int i = 0; i < 2; ++i) {
            int f = tid + i * 512;
            int row = f >> 3, c16 = f & 7;
            uint4 v = *(const uint4*)(Wt + (size_t)(n0 + row) * DMODEL + k0 + c16 * 8);
            *(uint4*)(smB + swz(row, c16)) = v;
        }
        __syncthreads();
#pragma unroll
        for (int ks = 0; ks < 2; ++ks) {
            bf16x8 a[4], bb[2];
#pragma unroll
            for (int mi = 0; mi < 4; ++mi)
                a[mi] = *(const bf16x8*)(smA + swz(wr * 64 + mi * 16 + lr, lg + ks * 4));
#pragma unroll
            for (int ni = 0; ni < 2; ++ni)
                bb[ni] = *(const bf16x8*)(smB + swz(wc * 32 + ni * 16 + lr, lg + ks * 4));
#pragma unroll
            for (int mi = 0; mi < 4; ++mi)
#pragma unroll
                for (int ni = 0; ni < 2; ++ni)
                    acc[mi][ni] = __builtin_amdgcn_mfma_f32_16x16x32_bf16(a[mi], bb[ni], acc[mi][ni], 0, 0, 0);
        }
    }
#pragma unroll
    for (int mi = 0; mi < 4; ++mi) {
#pragma unroll
        for (int ni = 0; ni < 2; ++ni) {
            const int col = n0 + wc * 32 + ni * 16 + lr;
            const int row0 = m0 + wr * 64 + mi * 16 + lg * 4;
            if (MODE == 0) {
                const bool isG = col >= DMODEL;
                const int c = isG ? col - DMODEL : col;
                const float bb = isG ? bias1[c] : bias0[c];
#pragma unroll
                for (int j = 0; j < 4; ++j) {
                    float x = acc[mi][ni][j] + bb;
                    bf16_t r = isG ? (bf16_t)(1.0f / (1.0f + __expf(-x)))
                                   : (bf16_t)(x * QKS_L2E);
                    (isG ? out1 : out0)[(size_t)(row0 + j) * DMODEL + c] = r;
                }
            } else if (MODE == 1) {
                const float bb = bias0[col];
#pragma unroll
                for (int j = 0; j < 4; ++j)
                    out0[(size_t)(row0 + j) * DMODEL + col] = (bf16_t)(acc[mi][ni][j] + bb);
            } else {
                const float bb = bias0[col];
                const int b = row0 >> 11, key = row0 & (SEQ - 1);
                const int h = col >> 6, d = col & 63;
                bf16x4 r;
#pragma unroll
                for (int j = 0; j < 4; ++j) r[j] = (bf16_t)(acc[mi][ni][j] + bb);
                *(bf16x4*)(out0 + ((size_t)(b * HEADS + h) * HDIM + d) * SEQ + key) = r;
            }
        }
    }
}

// ---------------------------------------------------------------------------
// K2: flash attention (softmax(QK^T)@V; bias term via K2b). Scores are tiny
// (|s_log2| < ~1.5) => NO max-tracking: p=exp2(s), per-lane partial row-sums,
// single cross-lane reduction at the end. wq_ carries 0.125*log2(e).
// Staging: R2-measured no-spill structure (direct in-loop load -> LDS, single
// buffer). The R4 register double-buffer caused scratch spill (R6/R7: VGPR
// squeezed to 48-60, 284-305 MB/dispatch scratch writes, 157 us) -- reverted.
// ---------------------------------------------------------------------------
__global__ __launch_bounds__(256) void attn_kernel(
    const bf16_t* __restrict__ wq, const bf16_t* __restrict__ wk,
    const bf16_t* __restrict__ wvt, bf16_t* __restrict__ attn_o)
{
    __shared__ __align__(16) char smK[8192];
    __shared__ __align__(16) char smV[8192];
    __shared__ __align__(16) char smP[8192];
    const int tid = threadIdx.x;
    const int lane = tid & 63, w = tid >> 6;
    const int bh = blockIdx.x & 31;
    const int qt = blockIdx.x >> 5;
    const int b = bh >> 3, h = bh & 7;
    const int q0 = qt << 6;
    const int lr = lane & 15, lg = lane >> 4;

    bf16x8 qf[2];
    {
        int row = q0 + w * 16 + lr;
        const bf16_t* p = wq + (size_t)(b * SEQ + row) * DMODEL + h * HDIM + lg * 8;
        qf[0] = *(const bf16x8*)(p);
        qf[1] = *(const bf16x8*)(p + 32);
    }
    const bf16_t* kbase = wk + (size_t)b * SEQ * DMODEL + h * HDIM;
    const bf16_t* vbase = wvt + (size_t)(b * HEADS + h) * HDIM * SEQ;
    // staging coords: i in {0,1}; f = tid + i*256; row = f>>3 (0..63), c16 = f&7
    const int srow0 = tid >> 3,         sc0 = tid & 7;
    const int srow1 = (tid + 256) >> 3, sc1 = (tid + 256) & 7;

    float lsum[4] = {0.f, 0.f, 0.f, 0.f};
    f32x4 oacc[4] = {};

    for (int kt = 0; kt < SEQ / 64; ++kt) {
        const int k0 = kt * 64;
        __syncthreads();   // previous tile's LDS reads complete
        {
            uint4 vk0 = *(const uint4*)(kbase + (size_t)(k0 + srow0) * DMODEL + sc0 * 8);
            uint4 vk1 = *(const uint4*)(kbase + (size_t)(k0 + srow1) * DMODEL + sc1 * 8);
            uint4 vv0 = *(const uint4*)(vbase + (size_t)srow0 * SEQ + k0 + sc0 * 8);
            uint4 vv1 = *(const uint4*)(vbase + (size_t)srow1 * SEQ + k0 + sc1 * 8);
            *(uint4*)(smK + swz(srow0, sc0)) = vk0;
            *(uint4*)(smK + swz(srow1, sc1)) = vk1;
            *(uint4*)(smV + swz(srow0, sc0)) = vv0;
            *(uint4*)(smV + swz(srow1, sc1)) = vv1;
        }
        __syncthreads();

        // S = Q @ K^T (log2-domain): rows=q (16), cols=keys (64)
        f32x4 s[4] = {};
#pragma unroll
        for (int ks = 0; ks < 2; ++ks) {
#pragma unroll
            for (int nf = 0; nf < 4; ++nf) {
                bf16x8 kbf = *(const bf16x8*)(smK + swz(nf * 16 + lr, lg + ks * 4));
                s[nf] = __builtin_amdgcn_mfma_f32_16x16x32_bf16(qf[ks], kbf, s[nf], 0, 0, 0);
            }
        }
        // p = 2^s ; accumulate per-lane partial row sums (reduce once at end)
#pragma unroll
        for (int nf = 0; nf < 4; ++nf) {
#pragma unroll
            for (int j = 0; j < 4; ++j) {
                float p = __builtin_amdgcn_exp2f(s[nf][j]);
                s[nf][j] = p;
                lsum[j] += p;
            }
        }
        // P -> per-wave LDS (bf16, swizzled); wave-private, no barrier needed
        char* pbase = smP + w * 2048;
#pragma unroll
        for (int nf = 0; nf < 4; ++nf) {
            int col = nf * 16 + lr;
#pragma unroll
            for (int j = 0; j < 4; ++j) {
                int row = lg * 4 + j;
                *(bf16_t*)(pbase + swz(row, col >> 3) + ((col & 7) << 1)) = (bf16_t)s[nf][j];
            }
        }
        // O += P @ V
#pragma unroll
        for (int ks = 0; ks < 2; ++ks) {
            bf16x8 pa = *(const bf16x8*)(pbase + swz(lr, lg + ks * 4));
#pragma unroll
            for (int nf = 0; nf < 4; ++nf) {
                bf16x8 vb = *(const bf16x8*)(smV + swz(nf * 16 + lr, lg + ks * 4));
                oacc[nf] = __builtin_amdgcn_mfma_f32_16x16x32_bf16(pa, vb, oacc[nf], 0, 0, 0);
            }
        }
    }
    float rinv[4];
#pragma unroll
    for (int j = 0; j < 4; ++j) {
        float t = lsum[j];
#pragma unroll
        for (int off = 1; off < 16; off <<= 1) t += __shfl_xor(t, off);
        rinv[j] = 1.0f / t;
    }
#pragma unroll
    for (int nf = 0; nf < 4; ++nf) {
        int col = h * HDIM + nf * 16 + lr;
#pragma unroll
        for (int j = 0; j < 4; ++j) {
            int row = q0 + w * 16 + lg * 4 + j;
            attn_o[(size_t)(b * SEQ + row) * DMODEL + col] = (bf16_t)(oacc[nf][j] * rinv[j]);
        }
    }
}

// ---------------------------------------------------------------------------
// K2b: Bv = bias @ wv   (batched: M=2048, N=512, K=2048), 128x128 tile
// ---------------------------------------------------------------------------
__global__ __launch_bounds__(512) void biasv_gemm(
    const float* __restrict__ bias, const bf16_t* __restrict__ wvt,
    float* __restrict__ Bv)
{
    __shared__ __align__(16) char smA[16384];
    __shared__ __align__(16) char smB[16384];
    const int tid = threadIdx.x;
    const int lane = tid & 63, w = tid >> 6;
    const int nt = blockIdx.x & 3;
    const int mt = (blockIdx.x >> 2) & 15;
    const int b = blockIdx.x >> 6;
    const int m0 = mt << 7, n0 = nt << 7;
    const int wr = w >> 2, wc = w & 3;
    const int lr = lane & 15, lg = lane >> 4;

    f32x4 acc[4][2] = {};
    for (int kb = 0; kb < SEQ / 64; ++kb) {
        const int k0 = kb * 64;
        __syncthreads();
#pragma unroll
        for (int i = 0; i < 4; ++i) {
            int f = tid + i * 512;
            int row = f >> 4, c4 = f & 15;
            float4 v = *(const float4*)(bias + ((size_t)b * SEQ + m0 + row) * SEQ + k0 + c4 * 4);
            *(bf16x4*)(smA + swz(row, c4 >> 1) + ((c4 & 1) << 3)) = cvt4(v);
        }
#pragma unroll
        for (int i = 0; i < 2; ++i) {
            int f = tid + i * 512;
            int row = f >> 3, c16 = f & 7;
            int n = n0 + row;
            uint4 v = *(const uint4*)(wvt + ((size_t)(b * HEADS + (n >> 6)) * HDIM + (n & 63)) * SEQ + k0 + c16 * 8);
            *(uint4*)(smB + swz(row, c16)) = v;
        }
        __syncthreads();
#pragma unroll
        for (int ks = 0; ks < 2; ++ks) {
            bf16x8 a[4], bb[2];
#pragma unroll
            for (int mi = 0; mi < 4; ++mi)
                a[mi] = *(const bf16x8*)(smA + swz(wr * 64 + mi * 16 + lr, lg + ks * 4));
#pragma unroll
            for (int ni = 0; ni < 2; ++ni)
                bb[ni] = *(const bf16x8*)(smB + swz(wc * 32 + ni * 16 + lr, lg + ks * 4));
#pragma unroll
            for (int mi = 0; mi < 4; ++mi)
#pragma unroll
                for (int ni = 0; ni < 2; ++ni)
                    acc[mi][ni] = __builtin_amdgcn_mfma_f32_16x16x32_bf16(a[mi], bb[ni], acc[mi][ni], 0, 0, 0);
        }
    }
#pragma unroll
    for (int mi = 0; mi < 4; ++mi) {
#pragma unroll
        for (int ni = 0; ni < 2; ++ni) {
            int col = n0 + wc * 32 + ni * 16 + lr;
#pragma unroll
            for (int j = 0; j < 4; ++j) {
                int row = m0 + wr * 64 + mi * 16 + lg * 4 + j;
                Bv[((size_t)b * SEQ + row) * DMODEL + col] = acc[mi][ni][j];
            }
        }
    }
}

// ---------------------------------------------------------------------------
// K3: out = (g * (attn + Bv)) @ Wo + bo, 128x128 tile, fused A staging
// ---------------------------------------------------------------------------
__global__ __launch_bounds__(512) void out_gemm(
    const bf16_t* __restrict__ atn, const float* __restrict__ Bvp,
    const bf16_t* __restrict__ gg, const bf16_t* __restrict__ Wot,
    const float* __restrict__ bo, float* __restrict__ out)
{
    __shared__ __align__(16) char smA[16384];
    __shared__ __align__(16) char smB[16384];
    const int tid = threadIdx.x;
    const int lane = tid & 63, w = tid >> 6;
    const int nt = blockIdx.x & 3;
    const int mt = blockIdx.x >> 2;
    const int m0 = mt << 7, n0 = nt << 7;
    const int wr = w >> 2, wc = w & 3;
    const int lr = lane & 15, lg = lane >> 4;

    f32x4 acc[4][2] = {};
    for (int kb = 0; kb < 8; ++kb) {
        const int k0 = kb * 64;
        __syncthreads();
#pragma unroll
        for (int i = 0; i < 2; ++i) {
            int f = tid + i * 512;
            int row = f >> 3, c8 = f & 7;
            size_t idx = (size_t)(m0 + row) * DMODEL + k0 + c8 * 8;
            bf16x8 a8 = *(const bf16x8*)(atn + idx);
            bf16x8 g8 = *(const bf16x8*)(gg + idx);
            float4 blo = *(const float4*)(Bvp + idx);
            float4 bhi = *(const float4*)(Bvp + idx + 4);
            bf16x8 r;
            r[0] = (bf16_t)((float)g8[0] * ((float)a8[0] + blo.x));
            r[1] = (bf16_t)((float)g8[1] * ((float)a8[1] + blo.y));
            r[2] = (bf16_t)((float)g8[2] * ((float)a8[2] + blo.z));
            r[3] = (bf16_t)((float)g8[3] * ((float)a8[3] + blo.w));
            r[4] = (bf16_t)((float)g8[4] * ((float)a8[4] + bhi.x));
            r[5] = (bf16_t)((float)g8[5] * ((float)a8[5] + bhi.y));
            r[6] = (bf16_t)((float)g8[6] * ((float)a8[6] + bhi.z));
            r[7] = (bf16_t)((float)g8[7] * ((float)a8[7] + bhi.w));
            *(bf16x8*)(smA + swz(row, c8)) = r;
        }
#pragma unroll
        for (int i = 0; i < 2; ++i) {
            int f = tid + i * 512;
            int row = f >> 3, c16 = f & 7;
            uint4 v = *(const uint4*)(Wot + (size_t)(n0 + row) * DMODEL + k0 + c16 * 8);
            *(uint4*)(smB + swz(row, c16)) = v;
        }
        __syncthreads();
#pragma unroll
        for (int ks = 0; ks < 2; ++ks) {
            bf16x8 a[4], bb[2];
#pragma unroll
            for (int mi = 0; mi < 4; ++mi)
                a[mi] = *(const bf16x8*)(smA + swz(wr * 64 + mi * 16 + lr, lg + ks * 4));
#pragma unroll
            for (int ni = 0; ni < 2; ++ni)
                bb[ni] = *(const bf16x8*)(smB + swz(wc * 32 + ni * 16 + lr, lg + ks * 4));
#pragma unroll
            for (int mi = 0; mi < 4; ++mi)
#pragma unroll
                for (int ni = 0; ni < 2; ++ni)
                    acc[mi][ni] = __builtin_amdgcn_mfma_f32_16x16x32_bf16(a[mi], bb[ni], acc[mi][ni], 0, 0, 0);
        }
    }
#pragma unroll
    for (int mi = 0; mi < 4; ++mi) {
#pragma unroll
        for (int ni = 0; ni < 2; ++ni) {
            int col = n0 + wc * 32 + ni * 16 + lr;
            float bb = bo[col];
#pragma unroll
            for (int j = 0; j < 4; ++j) {
                int row = m0 + wr * 64 + mi * 16 + lg * 4 + j;
                out[(size_t)row * DMODEL + col] = acc[mi][ni][j] + bb;
            }
        }
    }
}

// ---------------------------------------------------------------------------
extern "C" void kernel_launch(void* const* d_in, const int* in_sizes, int n_in,
                              void* d_out, int out_size, void* d_ws, size_t ws_size,
                              hipStream_t stream)
{
    const float* q    = (const float*)d_in[0];
    const float* k    = (const float*)d_in[1];
    const float* v    = (const float*)d_in[2];
    const float* bias = (const float*)d_in[3];
    const float* Wq   = (const float*)d_in[4];
    const float* bq   = (const float*)d_in[5];
    const float* Wk   = (const float*)d_in[6];
    const float* bk   = (const float*)d_in[7];
    const float* Wv   = (const float*)d_in[8];
    const float* bv   = (const float*)d_in[9];
    const float* Wg   = (const float*)d_in[10];
    const float* bg   = (const float*)d_in[11];
    const float* Wo   = (const float*)d_in[12];
    const float* bo   = (const float*)d_in[13];
    float* out = (float*)d_out;

    char* ws = (char*)d_ws;
    const size_t WSZ = (size_t)DMODEL * DMODEL;          // 262144 elems
    const size_t TOK = (size_t)NB * SEQ * DMODEL;        // 4.19M elems
    bf16_t* Wt   = (bf16_t*)ws;                          // [Wq;Wg;Wk;Wv;Wo]_t bf16
    bf16_t* wq_  = (bf16_t*)(ws + 5 * WSZ * 2);          // (B,Q,512) bf16, *0.125*log2e
    bf16_t* wk_  = wq_ + TOK;                            // (B,K,512) bf16
    bf16_t* wvt  = wk_ + TOK;                            // (B,H,64,K) bf16
    bf16_t* atn  = wvt + TOK;                            // (B,Q,512) bf16
    bf16_t* g_   = atn + TOK;                            // (B,Q,512) bf16
    float*  Bv_  = (float*)(g_ + TOK);                   // (B,Q,512) f32
    // total ws use: 2.6MB + 5*8MB + 16MB = ~58.6 MB

    prep_weights<<<320, 256, 0, stream>>>(Wq, Wg, Wk, Wv, Wo, Wt);
    proj_gemm<0><<<512, 512, 0, stream>>>(q, Wt,           bq, bg,      wq_, g_);
    proj_gemm<1><<<256, 512, 0, stream>>>(k, Wt + 2 * WSZ, bk, nullptr, wk_, nullptr);
    proj_gemm<2><<<256, 512, 0, stream>>>(v, Wt + 3 * WSZ, bv, nullptr, wvt, nullptr);
    attn_kernel<<<1024, 256, 0, stream>>>(wq_, wk_, wvt, atn);
    biasv_gemm<<<256, 512, 0, stream>>>(bias, wvt, Bv_);
    out_gemm<<<256, 512, 0, stream>>>(atn, Bv_, g_, Wt + 4 * WSZ, bo, out);
}

// Round 10
// 387.716 us; speedup vs baseline: 1.2662x; 1.0529x over previous
//
#include <hip/hip_runtime.h>
#include <hip/hip_bf16.h>

#define NB 4
#define SEQ 2048
#define DMODEL 512
#define HEADS 8
#define HDIM 64
// 0.125 * log2(e): scores come out in log2 domain -> exp2 is a single v_exp_f32
#define QKS_L2E 0.18033688011112042f

typedef __bf16 bf16_t;
typedef bf16_t bf16x8 __attribute__((ext_vector_type(8)));
typedef bf16_t bf16x4 __attribute__((ext_vector_type(4)));
typedef float f32x4 __attribute__((ext_vector_type(4)));

// XOR swizzle: rows are 64 bf16 = 128 B = 8x16B slots; spread column-slot by row&7.
__device__ __forceinline__ int swz(int row, int c16) {
    return (row << 7) + (((c16) ^ (row & 7)) << 4);
}

__device__ __forceinline__ bf16x4 cvt4(float4 v) {
    bf16x4 r;
    r[0] = (bf16_t)v.x; r[1] = (bf16_t)v.y; r[2] = (bf16_t)v.z; r[3] = (bf16_t)v.w;
    return r;
}

// async global -> LDS, 16B per lane. LDS dest is wave-uniform base + lane*16;
// swizzled layouts are achieved by pre-swizzling the per-lane GLOBAL address.
__device__ __forceinline__ void gl_lds16(const void* g, void* lds) {
    __builtin_amdgcn_global_load_lds(
        (const __attribute__((address_space(1))) void*)g,
        (__attribute__((address_space(3))) void*)lds, 16, 0, 0);
}

// ---------------------------------------------------------------------------
// K0: transpose + convert the 5 weight matrices (512x512 fp32 [k][n]) into
//     bf16 [n][k]. Order: Wq, Wg, Wk, Wv, Wo  (Wq|Wg contiguous for fused P1)
// ---------------------------------------------------------------------------
__global__ __launch_bounds__(256) void prep_weights(
    const float* __restrict__ Wq, const float* __restrict__ Wg,
    const float* __restrict__ Wk, const float* __restrict__ Wv,
    const float* __restrict__ Wo, bf16_t* __restrict__ out)
{
    __shared__ float t[64][65];
    const int m  = blockIdx.x >> 6;
    const int t2 = blockIdx.x & 63;
    const int tr = t2 >> 3, tc = t2 & 7;   // tr: k-tile, tc: n-tile
    const float* W = (m == 0) ? Wq : (m == 1) ? Wg : (m == 2) ? Wk : (m == 3) ? Wv : Wo;
    const int r0 = threadIdx.x >> 6;  // 0..3
    const int c  = threadIdx.x & 63;
#pragma unroll
    for (int i = 0; i < 64; i += 4) {
        int row = i + r0;
        t[row][c] = W[(size_t)(tr * 64 + row) * DMODEL + tc * 64 + c];
    }
    __syncthreads();
    bf16_t* o = out + (size_t)m * (DMODEL * DMODEL);
#pragma unroll
    for (int i = 0; i < 64; i += 4) {
        int row = i + r0;
        o[(size_t)(tc * 64 + row) * DMODEL + tr * 64 + c] = (bf16_t)t[c][row];
    }
}

// ---------------------------------------------------------------------------
// K1: projection GEMM, 128x128 tile, 8 waves (512 thr), BK=64
// MODE 0: A=q, B=[Wq_t;Wg_t] (N=1024): col<512 -> wq bf16 *QKS_L2E; else sigmoid->g
// MODE 1: A=k, B=Wk_t (N=512): plain bf16
// MODE 2: A=v, B=Wv_t (N=512): bf16 transposed -> (B,H,HDIM,SEQ)
// ---------------------------------------------------------------------------
template <int MODE>
__global__ __launch_bounds__(512) void proj_gemm(
    const float* __restrict__ A, const bf16_t* __restrict__ Wt,
    const float* __restrict__ bias0, const float* __restrict__ bias1,
    bf16_t* __restrict__ out0, bf16_t* __restrict__ out1)
{
    constexpr int NT = (MODE == 0) ? 8 : 4;
    __shared__ __align__(16) char smA[16384];
    __shared__ __align__(16) char smB[16384];
    const int tid = threadIdx.x;
    const int lane = tid & 63, w = tid >> 6;
    const int nt = blockIdx.x & (NT - 1);
    const int mt = blockIdx.x / NT;
    const int m0 = mt << 7, n0 = nt << 7;
    const int wr = w >> 2, wc = w & 3;
    const int lr = lane & 15, lg = lane >> 4;

    f32x4 acc[4][2] = {};
    for (int kb = 0; kb < 8; ++kb) {
        const int k0 = kb * 64;
        __syncthreads();
#pragma unroll
        for (int i = 0; i < 4; ++i) {
            int f = tid + i * 512;
            int row = f >> 4, c4 = f & 15;
            float4 v = *(const float4*)(A + (size_t)(m0 + row) * DMODEL + k0 + c4 * 4);
            *(bf16x4*)(smA + swz(row, c4 >> 1) + ((c4 & 1) << 3)) = cvt4(v);
        }
#pragma unroll
        for (int i = 0; i < 2; ++i) {
            int f = tid + i * 512;
            int row = f >> 3, c16 = f & 7;
            uint4 v = *(const uint4*)(Wt + (size_t)(n0 + row) * DMODEL + k0 + c16 * 8);
            *(uint4*)(smB + swz(row, c16)) = v;
        }
        __syncthreads();
#pragma unroll
        for (int ks = 0; ks < 2; ++ks) {
            bf16x8 a[4], bb[2];
#pragma unroll
            for (int mi = 0; mi < 4; ++mi)
                a[mi] = *(const bf16x8*)(smA + swz(wr * 64 + mi * 16 + lr, lg + ks * 4));
#pragma unroll
            for (int ni = 0; ni < 2; ++ni)
                bb[ni] = *(const bf16x8*)(smB + swz(wc * 32 + ni * 16 + lr, lg + ks * 4));
#pragma unroll
            for (int mi = 0; mi < 4; ++mi)
#pragma unroll
                for (int ni = 0; ni < 2; ++ni)
                    acc[mi][ni] = __builtin_amdgcn_mfma_f32_16x16x32_bf16(a[mi], bb[ni], acc[mi][ni], 0, 0, 0);
        }
    }
#pragma unroll
    for (int mi = 0; mi < 4; ++mi) {
#pragma unroll
        for (int ni = 0; ni < 2; ++ni) {
            const int col = n0 + wc * 32 + ni * 16 + lr;
            const int row0 = m0 + wr * 64 + mi * 16 + lg * 4;
            if (MODE == 0) {
                const bool isG = col >= DMODEL;
                const int c = isG ? col - DMODEL : col;
                const float bb = isG ? bias1[c] : bias0[c];
#pragma unroll
                for (int j = 0; j < 4; ++j) {
                    float x = acc[mi][ni][j] + bb;
                    bf16_t r = isG ? (bf16_t)(1.0f / (1.0f + __expf(-x)))
                                   : (bf16_t)(x * QKS_L2E);
                    (isG ? out1 : out0)[(size_t)(row0 + j) * DMODEL + c] = r;
                }
            } else if (MODE == 1) {
                const float bb = bias0[col];
#pragma unroll
                for (int j = 0; j < 4; ++j)
                    out0[(size_t)(row0 + j) * DMODEL + col] = (bf16_t)(acc[mi][ni][j] + bb);
            } else {
                const float bb = bias0[col];
                const int b = row0 >> 11, key = row0 & (SEQ - 1);
                const int h = col >> 6, d = col & 63;
                bf16x4 r;
#pragma unroll
                for (int j = 0; j < 4; ++j) r[j] = (bf16_t)(acc[mi][ni][j] + bb);
                *(bf16x4*)(out0 + ((size_t)(b * HEADS + h) * HDIM + d) * SEQ + key) = r;
            }
        }
    }
}

// ---------------------------------------------------------------------------
// K2: flash attention (softmax(QK^T)@V; bias term via K2b). Scores are tiny
// (|s_log2| < ~1.5) => NO max-tracking: p=exp2(s), per-lane partial row-sums,
// single cross-lane reduction at the end. wq_ carries 0.125*log2(e).
// Staging: R2-measured no-spill structure (direct in-loop load -> LDS).
// ---------------------------------------------------------------------------
__global__ __launch_bounds__(256) void attn_kernel(
    const bf16_t* __restrict__ wq, const bf16_t* __restrict__ wk,
    const bf16_t* __restrict__ wvt, bf16_t* __restrict__ attn_o)
{
    __shared__ __align__(16) char smK[8192];
    __shared__ __align__(16) char smV[8192];
    __shared__ __align__(16) char smP[8192];
    const int tid = threadIdx.x;
    const int lane = tid & 63, w = tid >> 6;
    const int bh = blockIdx.x & 31;
    const int qt = blockIdx.x >> 5;
    const int b = bh >> 3, h = bh & 7;
    const int q0 = qt << 6;
    const int lr = lane & 15, lg = lane >> 4;

    bf16x8 qf[2];
    {
        int row = q0 + w * 16 + lr;
        const bf16_t* p = wq + (size_t)(b * SEQ + row) * DMODEL + h * HDIM + lg * 8;
        qf[0] = *(const bf16x8*)(p);
        qf[1] = *(const bf16x8*)(p + 32);
    }
    const bf16_t* kbase = wk + (size_t)b * SEQ * DMODEL + h * HDIM;
    const bf16_t* vbase = wvt + (size_t)(b * HEADS + h) * HDIM * SEQ;
    const int srow0 = tid >> 3,         sc0 = tid & 7;
    const int srow1 = (tid + 256) >> 3, sc1 = (tid + 256) & 7;

    float lsum[4] = {0.f, 0.f, 0.f, 0.f};
    f32x4 oacc[4] = {};

    for (int kt = 0; kt < SEQ / 64; ++kt) {
        const int k0 = kt * 64;
        __syncthreads();   // previous tile's LDS reads complete
        {
            uint4 vk0 = *(const uint4*)(kbase + (size_t)(k0 + srow0) * DMODEL + sc0 * 8);
            uint4 vk1 = *(const uint4*)(kbase + (size_t)(k0 + srow1) * DMODEL + sc1 * 8);
            uint4 vv0 = *(const uint4*)(vbase + (size_t)srow0 * SEQ + k0 + sc0 * 8);
            uint4 vv1 = *(const uint4*)(vbase + (size_t)srow1 * SEQ + k0 + sc1 * 8);
            *(uint4*)(smK + swz(srow0, sc0)) = vk0;
            *(uint4*)(smK + swz(srow1, sc1)) = vk1;
            *(uint4*)(smV + swz(srow0, sc0)) = vv0;
            *(uint4*)(smV + swz(srow1, sc1)) = vv1;
        }
        __syncthreads();

        f32x4 s[4] = {};
#pragma unroll
        for (int ks = 0; ks < 2; ++ks) {
#pragma unroll
            for (int nf = 0; nf < 4; ++nf) {
                bf16x8 kbf = *(const bf16x8*)(smK + swz(nf * 16 + lr, lg + ks * 4));
                s[nf] = __builtin_amdgcn_mfma_f32_16x16x32_bf16(qf[ks], kbf, s[nf], 0, 0, 0);
            }
        }
#pragma unroll
        for (int nf = 0; nf < 4; ++nf) {
#pragma unroll
            for (int j = 0; j < 4; ++j) {
                float p = __builtin_amdgcn_exp2f(s[nf][j]);
                s[nf][j] = p;
                lsum[j] += p;
            }
        }
        char* pbase = smP + w * 2048;
#pragma unroll
        for (int nf = 0; nf < 4; ++nf) {
            int col = nf * 16 + lr;
#pragma unroll
            for (int j = 0; j < 4; ++j) {
                int row = lg * 4 + j;
                *(bf16_t*)(pbase + swz(row, col >> 3) + ((col & 7) << 1)) = (bf16_t)s[nf][j];
            }
        }
#pragma unroll
        for (int ks = 0; ks < 2; ++ks) {
            bf16x8 pa = *(const bf16x8*)(pbase + swz(lr, lg + ks * 4));
#pragma unroll
            for (int nf = 0; nf < 4; ++nf) {
                bf16x8 vb = *(const bf16x8*)(smV + swz(nf * 16 + lr, lg + ks * 4));
                oacc[nf] = __builtin_amdgcn_mfma_f32_16x16x32_bf16(pa, vb, oacc[nf], 0, 0, 0);
            }
        }
    }
    float rinv[4];
#pragma unroll
    for (int j = 0; j < 4; ++j) {
        float t = lsum[j];
#pragma unroll
        for (int off = 1; off < 16; off <<= 1) t += __shfl_xor(t, off);
        rinv[j] = 1.0f / t;
    }
#pragma unroll
    for (int nf = 0; nf < 4; ++nf) {
        int col = h * HDIM + nf * 16 + lr;
#pragma unroll
        for (int j = 0; j < 4; ++j) {
            int row = q0 + w * 16 + lg * 4 + j;
            attn_o[(size_t)(b * SEQ + row) * DMODEL + col] = (bf16_t)(oacc[nf][j] * rinv[j]);
        }
    }
}

// ---------------------------------------------------------------------------
// K2b: Bv = bias @ wv  (batched: M=2048, N=512, K=2048), 128x128 tile.
// v2: async 2-phase pipeline. global_load_lds (16B) double-buffered staging;
// next tile's loads issue BEFORE computing the current tile; the single
// __syncthreads per k-step (compiler emits vmcnt(0) before s_barrier) drains
// them after compute. bias stays fp32 in LDS (gl_lds can't convert) and is
// converted to bf16 at fragment-read time (VALU had 95% headroom).
// Swizzles preserved by pre-swizzling the per-lane GLOBAL source address.
// XCD-swizzled block ids: each XCD covers 8 m-slabs x all 4 n-tiles so the
// bias slab re-reads hit that XCD's L2 (R9: 139MB FETCH = ~2x bias re-fetch).
// ---------------------------------------------------------------------------
__global__ __launch_bounds__(512) void biasv_gemm(
    const float* __restrict__ bias, const bf16_t* __restrict__ wvt,
    float* __restrict__ Bv)
{
    // dbuf layout: buf i at sm + i*49152 { A: 128x64 f32 = 32KB, B(+32768): 128x64 bf16 = 16KB }
    __shared__ __align__(16) char sm[98304];
    const int tid = threadIdx.x;
    const int lane = tid & 63, w = tid >> 6;
    const int bid = (int)blockIdx.x;
    const int swzb = (bid & 7) * 32 + (bid >> 3);   // bijective, 256 % 8 == 0
    const int nt = swzb & 3;
    const int mt = (swzb >> 2) & 15;
    const int b  = swzb >> 6;
    const int m0 = mt << 7, n0 = nt << 7;
    const int wr = w >> 2, wc = w & 3;
    const int lr = lane & 15, lg = lane >> 4;

    const float*  Asrc = bias + ((size_t)b * SEQ + m0) * SEQ;    // [128][2048] f32
    const bf16_t* Bsrc = wvt + ((size_t)b * DMODEL + n0) * SEQ;  // [128][2048] bf16

    // staging lane coords (LDS linear dest; source pre-swizzled)
    const int aLr = lane >> 4;                 // A: row-within-chunk 0..3
    const int aS  = lane & 15;                 // A: 16B-slot 0..15
    const int bLr = lane >> 3;                 // B: row-within-chunk 0..7
    const int bC16 = (lane & 7) ^ bLr;         // B: pre-swizzled 16B-slot

    auto STAGE = [&](int kb, char* bufA, char* bufB) {
        const int k0 = kb * 64;
#pragma unroll
        for (int i = 0; i < 4; ++i) {          // A: 32KB = 32 chunks, 4/wave
            const int c = (w << 2) + i;
            const int row = (c << 2) + aLr;    // 0..127
            const int sc = aS ^ (row & 15);    // f32 row = 256B = 16 slots
            gl_lds16(Asrc + (size_t)row * SEQ + k0 + sc * 4, bufA + (c << 10));
        }
#pragma unroll
        for (int i = 0; i < 2; ++i) {          // B: 16KB = 16 chunks, 2/wave
            const int c = (w << 1) + i;
            const int row = (c << 3) + bLr;    // 0..127 ; row&7 == bLr
            gl_lds16(Bsrc + (size_t)row * SEQ + k0 + bC16 * 8, bufB + (c << 10));
        }
    };

    f32x4 acc[4][2] = {};
    STAGE(0, sm, sm + 32768);
    __syncthreads();                           // vmcnt(0) drain emitted by compiler
    int cur = 0;
    for (int kb = 0; kb < SEQ / 64; ++kb) {
        const int coff = cur * 49152;
        char* curA = sm + coff;
        char* curB = sm + 32768 + coff;
        if (kb + 1 < SEQ / 64) {
            const int noff = 49152 - coff;
            STAGE(kb + 1, sm + noff, sm + 32768 + noff);   // async, in flight during compute
        }
#pragma unroll
        for (int ks = 0; ks < 2; ++ks) {
            bf16x8 a[4], bb[2];
#pragma unroll
            for (int mi = 0; mi < 4; ++mi) {
                const int row = wr * 64 + mi * 16 + lr;    // row & 15 == lr
                const int kk = lg + ks * 4;                // 8-elem group 0..7
                const char* rbase = curA + (row << 8);
                float4 lo = *(const float4*)(rbase + (((kk * 2)     ^ lr) << 4));
                float4 hi = *(const float4*)(rbase + (((kk * 2 + 1) ^ lr) << 4));
                bf16x8 av;
                av[0] = (bf16_t)lo.x; av[1] = (bf16_t)lo.y; av[2] = (bf16_t)lo.z; av[3] = (bf16_t)lo.w;
                av[4] = (bf16_t)hi.x; av[5] = (bf16_t)hi.y; av[6] = (bf16_t)hi.z; av[7] = (bf16_t)hi.w;
                a[mi] = av;
            }
#pragma unroll
            for (int ni = 0; ni < 2; ++ni)
                bb[ni] = *(const bf16x8*)(curB + swz(wc * 32 + ni * 16 + lr, lg + ks * 4));
#pragma unroll
            for (int mi = 0; mi < 4; ++mi)
#pragma unroll
                for (int ni = 0; ni < 2; ++ni)
                    acc[mi][ni] = __builtin_amdgcn_mfma_f32_16x16x32_bf16(a[mi], bb[ni], acc[mi][ni], 0, 0, 0);
        }
        __syncthreads();                       // drains next-tile vmcnt + this tile's lgkm
        cur ^= 1;
    }
#pragma unroll
    for (int mi = 0; mi < 4; ++mi) {
#pragma unroll
        for (int ni = 0; ni < 2; ++ni) {
            int col = n0 + wc * 32 + ni * 16 + lr;
#pragma unroll
            for (int j = 0; j < 4; ++j) {
                int row = m0 + wr * 64 + mi * 16 + lg * 4 + j;
                Bv[((size_t)b * SEQ + row) * DMODEL + col] = acc[mi][ni][j];
            }
        }
    }
}

// ---------------------------------------------------------------------------
// K3: out = (g * (attn + Bv)) @ Wo + bo, 128x128 tile, fused A staging
// ---------------------------------------------------------------------------
__global__ __launch_bounds__(512) void out_gemm(
    const bf16_t* __restrict__ atn, const float* __restrict__ Bvp,
    const bf16_t* __restrict__ gg, const bf16_t* __restrict__ Wot,
    const float* __restrict__ bo, float* __restrict__ out)
{
    __shared__ __align__(16) char smA[16384];
    __shared__ __align__(16) char smB[16384];
    const int tid = threadIdx.x;
    const int lane = tid & 63, w = tid >> 6;
    const int nt = blockIdx.x & 3;
    const int mt = blockIdx.x >> 2;
    const int m0 = mt << 7, n0 = nt << 7;
    const int wr = w >> 2, wc = w & 3;
    const int lr = lane & 15, lg = lane >> 4;

    f32x4 acc[4][2] = {};
    for (int kb = 0; kb < 8; ++kb) {
        const int k0 = kb * 64;
        __syncthreads();
#pragma unroll
        for (int i = 0; i < 2; ++i) {
            int f = tid + i * 512;
            int row = f >> 3, c8 = f & 7;
            size_t idx = (size_t)(m0 + row) * DMODEL + k0 + c8 * 8;
            bf16x8 a8 = *(const bf16x8*)(atn + idx);
            bf16x8 g8 = *(const bf16x8*)(gg + idx);
            float4 blo = *(const float4*)(Bvp + idx);
            float4 bhi = *(const float4*)(Bvp + idx + 4);
            bf16x8 r;
            r[0] = (bf16_t)((float)g8[0] * ((float)a8[0] + blo.x));
            r[1] = (bf16_t)((float)g8[1] * ((float)a8[1] + blo.y));
            r[2] = (bf16_t)((float)g8[2] * ((float)a8[2] + blo.z));
            r[3] = (bf16_t)((float)g8[3] * ((float)a8[3] + blo.w));
            r[4] = (bf16_t)((float)g8[4] * ((float)a8[4] + bhi.x));
            r[5] = (bf16_t)((float)g8[5] * ((float)a8[5] + bhi.y));
            r[6] = (bf16_t)((float)g8[6] * ((float)a8[6] + bhi.z));
            r[7] = (bf16_t)((float)g8[7] * ((float)a8[7] + bhi.w));
            *(bf16x8*)(smA + swz(row, c8)) = r;
        }
#pragma unroll
        for (int i = 0; i < 2; ++i) {
            int f = tid + i * 512;
            int row = f >> 3, c16 = f & 7;
            uint4 v = *(const uint4*)(Wot + (size_t)(n0 + row) * DMODEL + k0 + c16 * 8);
            *(uint4*)(smB + swz(row, c16)) = v;
        }
        __syncthreads();
#pragma unroll
        for (int ks = 0; ks < 2; ++ks) {
            bf16x8 a[4], bb[2];
#pragma unroll
            for (int mi = 0; mi < 4; ++mi)
                a[mi] = *(const bf16x8*)(smA + swz(wr * 64 + mi * 16 + lr, lg + ks * 4));
#pragma unroll
            for (int ni = 0; ni < 2; ++ni)
                bb[ni] = *(const bf16x8*)(smB + swz(wc * 32 + ni * 16 + lr, lg + ks * 4));
#pragma unroll
            for (int mi = 0; mi < 4; ++mi)
#pragma unroll
                for (int ni = 0; ni < 2; ++ni)
                    acc[mi][ni] = __builtin_amdgcn_mfma_f32_16x16x32_bf16(a[mi], bb[ni], acc[mi][ni], 0, 0, 0);
        }
    }
#pragma unroll
    for (int mi = 0; mi < 4; ++mi) {
#pragma unroll
        for (int ni = 0; ni < 2; ++ni) {
            int col = n0 + wc * 32 + ni * 16 + lr;
            float bb = bo[col];
#pragma unroll
            for (int j = 0; j < 4; ++j) {
                int row = m0 + wr * 64 + mi * 16 + lg * 4 + j;
                out[(size_t)row * DMODEL + col] = acc[mi][ni][j] + bb;
            }
        }
    }
}

// ---------------------------------------------------------------------------
extern "C" void kernel_launch(void* const* d_in, const int* in_sizes, int n_in,
                              void* d_out, int out_size, void* d_ws, size_t ws_size,
                              hipStream_t stream)
{
    const float* q    = (const float*)d_in[0];
    const float* k    = (const float*)d_in[1];
    const float* v    = (const float*)d_in[2];
    const float* bias = (const float*)d_in[3];
    const float* Wq   = (const float*)d_in[4];
    const float* bq   = (const float*)d_in[5];
    const float* Wk   = (const float*)d_in[6];
    const float* bk   = (const float*)d_in[7];
    const float* Wv   = (const float*)d_in[8];
    const float* bv   = (const float*)d_in[9];
    const float* Wg   = (const float*)d_in[10];
    const float* bg   = (const float*)d_in[11];
    const float* Wo   = (const float*)d_in[12];
    const float* bo   = (const float*)d_in[13];
    float* out = (float*)d_out;

    char* ws = (char*)d_ws;
    const size_t WSZ = (size_t)DMODEL * DMODEL;          // 262144 elems
    const size_t TOK = (size_t)NB * SEQ * DMODEL;        // 4.19M elems
    bf16_t* Wt   = (bf16_t*)ws;                          // [Wq;Wg;Wk;Wv;Wo]_t bf16
    bf16_t* wq_  = (bf16_t*)(ws + 5 * WSZ * 2);          // (B,Q,512) bf16, *0.125*log2e
    bf16_t* wk_  = wq_ + TOK;                            // (B,K,512) bf16
    bf16_t* wvt  = wk_ + TOK;                            // (B,H,64,K) bf16
    bf16_t* atn  = wvt + TOK;                            // (B,Q,512) bf16
    bf16_t* g_   = atn + TOK;                            // (B,Q,512) bf16
    float*  Bv_  = (float*)(g_ + TOK);                   // (B,Q,512) f32
    // total ws use: 2.6MB + 5*8MB + 16MB = ~58.6 MB

    prep_weights<<<320, 256, 0, stream>>>(Wq, Wg, Wk, Wv, Wo, Wt);
    proj_gemm<0><<<512, 512, 0, stream>>>(q, Wt,           bq, bg,      wq_, g_);
    proj_gemm<1><<<256, 512, 0, stream>>>(k, Wt + 2 * WSZ, bk, nullptr, wk_, nullptr);
    proj_gemm<2><<<256, 512, 0, stream>>>(v, Wt + 3 * WSZ, bv, nullptr, wvt, nullptr);
    attn_kernel<<<1024, 256, 0, stream>>>(wq_, wk_, wvt, atn);
    biasv_gemm<<<256, 512, 0, stream>>>(bias, wvt, Bv_);
    out_gemm<<<256, 512, 0, stream>>>(atn, Bv_, g_, Wt + 4 * WSZ, bo, out);
}